// Round 1
// baseline (7037.711 us; speedup 1.0000x reference)
//
#include <hip/hip_runtime.h>
#include <math.h>

#define SEQ 512
#define BATCH 8
#define HID 768
#define G4 3072           // 4*HID
#define CHUNK 128
#define NEGV (-1000000000.0f)

__device__ __forceinline__ float sigm(float x) { return 1.0f / (1.0f + expf(-x)); }

__device__ __forceinline__ float wred(float x) {
#pragma unroll
  for (int off = 32; off > 0; off >>= 1) x += __shfl_xor(x, off, 64);
  return x;
}

// ---------------------------------------------------------------- init zeros
__global__ void k_init(float* __restrict__ hs, float* __restrict__ hcur,
                       float* __restrict__ ccur) {
  int i = blockIdx.x * blockDim.x + threadIdx.x;
  int stride = gridDim.x * blockDim.x;
  for (int idx = i; idx < BATCH * SEQ * HID; idx += stride) hs[idx] = 0.0f;
  if (i < 4 * BATCH * HID) hcur[i] = 0.0f;   // [parity][dir][b][HID]
  if (i < 2 * BATCH * HID) ccur[i] = 0.0f;   // [dir][b][HID]
}

// ------------------------------------------- L1 input projection, one chunk
// dir GEMM: rows (b*128+tl), cols 3072, K=768.  A=emb row (b, t(tl)), B=W_ih (n,k) row-major.
__global__ __launch_bounds__(256) void k_proj1(
    const float* __restrict__ emb,
    const float* __restrict__ w_f, const float* __restrict__ b_f,
    const float* __restrict__ w_r, const float* __restrict__ b_r,
    float* __restrict__ xs_f, float* __restrict__ xs_r, int chunk) {
  __shared__ float As[16][132];
  __shared__ float Bs[16][132];
  const int tid = threadIdx.x;
  const int bn0 = blockIdx.x * 128;       // col tile over 3072
  const int bb  = blockIdx.y;             // batch
  const int dir = blockIdx.z;
  const float* W    = dir ? w_r : w_f;
  const float* bias = dir ? b_r : b_f;
  float* xs = dir ? xs_r : xs_f;

  float acc[8][8];
#pragma unroll
  for (int i = 0; i < 8; i++)
#pragma unroll
    for (int j = 0; j < 8; j++) acc[i][j] = 0.0f;

  const int mload = tid & 127;            // row (=tl) within tile
  const int kq0   = tid >> 7;             // 0..1
  const int tglob = dir ? (SEQ - 1 - (chunk * CHUNK + mload)) : (chunk * CHUNK + mload);
  const float* arow = emb + (size_t)(bb * SEQ + tglob) * HID;
  const float* brow = W + (size_t)(bn0 + mload) * HID;
  const int tm = tid & 15, tn = tid >> 4;

  for (int kt = 0; kt < HID; kt += 16) {
#pragma unroll
    for (int rep = 0; rep < 2; rep++) {
      int kq = kq0 + rep * 2;             // 0..3
      float4 a = *(const float4*)(arow + kt + kq * 4);
      As[kq * 4 + 0][mload] = a.x; As[kq * 4 + 1][mload] = a.y;
      As[kq * 4 + 2][mload] = a.z; As[kq * 4 + 3][mload] = a.w;
      float4 b = *(const float4*)(brow + kt + kq * 4);
      Bs[kq * 4 + 0][mload] = b.x; Bs[kq * 4 + 1][mload] = b.y;
      Bs[kq * 4 + 2][mload] = b.z; Bs[kq * 4 + 3][mload] = b.w;
    }
    __syncthreads();
#pragma unroll
    for (int k = 0; k < 16; k++) {
      float4 a0 = *(const float4*)&As[k][tm * 8];
      float4 a1 = *(const float4*)&As[k][tm * 8 + 4];
      float4 b0 = *(const float4*)&Bs[k][tn * 8];
      float4 b1 = *(const float4*)&Bs[k][tn * 8 + 4];
      float av[8] = {a0.x, a0.y, a0.z, a0.w, a1.x, a1.y, a1.z, a1.w};
      float bv[8] = {b0.x, b0.y, b0.z, b0.w, b1.x, b1.y, b1.z, b1.w};
#pragma unroll
      for (int i = 0; i < 8; i++)
#pragma unroll
        for (int j = 0; j < 8; j++) acc[i][j] += av[i] * bv[j];
    }
    __syncthreads();
  }
#pragma unroll
  for (int i = 0; i < 8; i++) {
    int row = tm * 8 + i;                 // tl
    size_t base = (size_t)(bb * CHUNK + row) * G4 + bn0 + tn * 8;
#pragma unroll
    for (int j = 0; j < 8; j++) xs[base + j] = acc[i][j] + bias[bn0 + tn * 8 + j];
  }
}

// ---------------------------------------------------- L1 recurrence, 1 step
// grid (96, 2): 8 hidden j per block x 4 gates x 8 batches = 256 threads.
// hcur double-buffered on step parity (fixes intra-launch read/write race).
__global__ __launch_bounds__(256) void k_step1(
    const float* __restrict__ whh_f, const float* __restrict__ whh_r,
    const float* __restrict__ xs_f, const float* __restrict__ xs_r,
    float* __restrict__ hcur, float* __restrict__ ccur,
    float* __restrict__ hs_out, int sstep) {
  __shared__ float hsl[8 * 776];          // [b][k] padded (768%32==0 -> 8-way conflict otherwise)
  __shared__ float gsl[256];
  const int tid = threadIdx.x;
  const int dir = blockIdx.y;
  const int j0 = blockIdx.x * 8;
  const int b = tid & 7;
  const int g = (tid >> 3) & 3;
  const int jj = tid >> 5;
  const int r = g * HID + j0 + jj;
  const int par = sstep & 1;

  const float* hc = hcur + (size_t)par * (2 * BATCH * HID) + dir * (BATCH * HID);
  for (int i = tid; i < BATCH * HID; i += 256) {
    int bi = i / HID;
    int ki = i - bi * HID;
    hsl[bi * 776 + ki] = hc[i];
  }
  __syncthreads();

  const int tl = sstep & (CHUNK - 1);
  const float* xs = dir ? xs_r : xs_f;
  float acc = xs[(size_t)(b * CHUNK + tl) * G4 + r];

  const float4* wp = (const float4*)((dir ? whh_r : whh_f) + (size_t)r * HID);
  const float4* hp = (const float4*)(hsl + b * 776);
#pragma unroll 4
  for (int k4 = 0; k4 < HID / 4; k4++) {
    float4 w = wp[k4];
    float4 h = hp[k4];
    acc += w.x * h.x + w.y * h.y + w.z * h.z + w.w * h.w;
  }
  gsl[tid] = acc;
  __syncthreads();

  if (tid < 64) {
    int b2 = tid & 7, jj2 = tid >> 3;
    int j = j0 + jj2;
    float iv = gsl[jj2 * 32 + 0 * 8 + b2];
    float fv = gsl[jj2 * 32 + 1 * 8 + b2];
    float gv = gsl[jj2 * 32 + 2 * 8 + b2];
    float ov = gsl[jj2 * 32 + 3 * 8 + b2];
    int ci = dir * (BATCH * HID) + b2 * HID + j;
    float c = ccur[ci];
    c = sigm(fv) * c + sigm(iv) * tanhf(gv);
    float h = sigm(ov) * tanhf(c);
    ccur[ci] = c;
    hcur[(size_t)(par ^ 1) * (2 * BATCH * HID) + ci] = h;
    int t = dir ? (SEQ - 1 - sstep) : sstep;
    // fwd writes t=s, rev writes t=511-s: disjoint within a launch (511 odd),
    // exactly-once per (dir,t) across launches -> plain += accumulates hf+hr.
    hs_out[(size_t)(b2 * SEQ + t) * HID + j] += h;
  }
}

// --------------------------------------------------------- windowed attention
__global__ __launch_bounds__(64) void k_attn(
    const float* __restrict__ hs, const float* __restrict__ attn_w,
    const float* __restrict__ attn_b, float* __restrict__ att) {
  const int l = threadIdx.x;
  const int s = blockIdx.x, b = blockIdx.y;
  const float* hrow = hs + (size_t)(b * SEQ + s) * HID;
  float hbs[12], v[12];
  float u1p = 0.0f;
#pragma unroll
  for (int j = 0; j < 12; j++) {
    int d = l + 64 * j;
    float x = hrow[d];
    hbs[j] = x;
    u1p += x * attn_w[d];
    v[j] = attn_w[HID + d] + x * attn_w[2 * HID + d];
  }
  float u1 = wred(u1p) + attn_b[0];
  float sc[21];
  for (int o = 0; o < 21; o++) {
    int s2 = s + o - 10;
    if (s2 >= 0 && s2 < SEQ) {
      const float* h2 = hs + (size_t)(b * SEQ + s2) * HID;
      float p = 0.0f;
#pragma unroll
      for (int j = 0; j < 12; j++) p += h2[l + 64 * j] * v[j];
      sc[o] = wred(p) + u1;
    } else {
      sc[o] = NEGV;
    }
  }
  float m = sc[0];
#pragma unroll
  for (int o = 1; o < 21; o++) m = fmaxf(m, sc[o]);
  float sum = 0.0f;
#pragma unroll
  for (int o = 0; o < 21; o++) { sc[o] = expf(sc[o] - m); sum += sc[o]; }
  float inv = 1.0f / sum;
  float acc[12];
#pragma unroll
  for (int j = 0; j < 12; j++) acc[j] = 0.0f;
  for (int o = 0; o < 21; o++) {
    int s2 = s + o - 10;
    if (s2 < 0 || s2 >= SEQ) continue;
    float a = sc[o] * inv;
    const float* h2 = hs + (size_t)(b * SEQ + s2) * HID;
#pragma unroll
    for (int j = 0; j < 12; j++) acc[j] += a * h2[l + 64 * j];
  }
  float* orow = att + (size_t)(b * SEQ + s) * HID;
#pragma unroll
  for (int j = 0; j < 12; j++) orow[l + 64 * j] = acc[j];
}

// -------------------------------------------------------- L2 input projection
__global__ __launch_bounds__(256) void k_proj2(
    const float* __restrict__ hs, const float* __restrict__ att,
    const float* __restrict__ w2f, const float* __restrict__ b2f,
    const float* __restrict__ w2r, const float* __restrict__ b2r,
    float* __restrict__ xs2) {
  __shared__ __align__(16) float x2[2 * HID];
  __shared__ float part[32][9];
  const int tid = threadIdx.x;
  const int s = blockIdx.x, b = blockIdx.y;
  size_t base = (size_t)(b * SEQ + s) * HID;
  for (int i = tid; i < 2 * HID; i += 256)
    x2[i] = (i < HID) ? hs[base + i] : att[base + i - HID];
  __syncthreads();
  const int gid = tid & 31, pp = tid >> 5;
  const int d = gid >> 4, g = gid & 15;
  const float4* w4 = (const float4*)((d ? w2r : w2f) + (size_t)g * (2 * HID));
  const float4* x4 = (const float4*)x2;
  float p = 0.0f;
  for (int e = pp * 48; e < pp * 48 + 48; e++) {
    float4 xv = x4[e];
    float4 wv = w4[e];
    p += xv.x * wv.x + xv.y * wv.y + xv.z * wv.z + xv.w * wv.w;
  }
  part[gid][pp] = p;
  __syncthreads();
  if (tid < 32) {
    float sumv = (d ? b2r : b2f)[g];
#pragma unroll
    for (int q = 0; q < 8; q++) sumv += part[gid][q];
    xs2[(size_t)((d * BATCH + b) * SEQ + s) * 16 + g] = sumv;
  }
}

// ------------------------------------------------------------- L2 recurrence
__global__ __launch_bounds__(256) void k_rec2(
    const float* __restrict__ xs2,
    const float* __restrict__ whh_f, const float* __restrict__ whh_r,
    float* __restrict__ h2) {
  __shared__ float hsh[2 * BATCH * 4];
  __shared__ float gsh[2 * BATCH * 16];
  const int tid = threadIdx.x;
  const int d = tid >> 7, b = (tid >> 4) & 7, g = tid & 15;
  const float* whh = (d ? whh_r : whh_f) + g * 4;
  const float w0 = whh[0], w1 = whh[1], w2 = whh[2], w3 = whh[3];
  const int hb = d * BATCH + b;
  if (g < 4) hsh[hb * 4 + g] = 0.0f;
  float c = 0.0f;
  __syncthreads();
  const float* xrow = xs2 + (size_t)hb * SEQ * 16 + g;
  for (int st = 0; st < SEQ; st++) {
    int t = d ? (SEQ - 1 - st) : st;
    float gv = xrow[t * 16] + w0 * hsh[hb * 4 + 0] + w1 * hsh[hb * 4 + 1] +
               w2 * hsh[hb * 4 + 2] + w3 * hsh[hb * 4 + 3];
    gsh[hb * 16 + g] = gv;
    __syncthreads();
    if (g < 4) {
      float iv = gsh[hb * 16 + g];
      float fv = gsh[hb * 16 + 4 + g];
      float gg = gsh[hb * 16 + 8 + g];
      float ov = gsh[hb * 16 + 12 + g];
      c = sigm(fv) * c + sigm(iv) * tanhf(gg);
      float h = sigm(ov) * tanhf(c);
      hsh[hb * 4 + g] = h;
      h2[((size_t)hb * SEQ + t) * 4 + g] = h;
    }
    __syncthreads();
  }
}

// ------------------------------------------------------------------ em = f+r
__global__ void k_em(const float* __restrict__ h2, float* __restrict__ out) {
  int i = blockIdx.x * 256 + threadIdx.x;
  if (i < BATCH * SEQ * 4) out[BATCH * SEQ + i] = h2[i] + h2[BATCH * SEQ * 4 + i];
}

// ------------------------------------------------------------------- viterbi
__global__ __launch_bounds__(32) void k_viterbi(
    float* __restrict__ out, const float* __restrict__ start,
    const float* __restrict__ endw, const float* __restrict__ trans) {
  __shared__ unsigned char bp[SEQ - 1][32];
  const int l = threadIdx.x;
  const int b = l >> 2, j = l & 3;
  const float* em = out + BATCH * SEQ;
  const float tr0 = trans[0 * 4 + j], tr1 = trans[1 * 4 + j];
  const float tr2 = trans[2 * 4 + j], tr3 = trans[3 * 4 + j];
  float score = start[j] + em[((size_t)b * SEQ + 0) * 4 + j];
  for (int t = 1; t < SEQ; t++) {
    float s0 = __shfl(score, b * 4 + 0, 64);
    float s1 = __shfl(score, b * 4 + 1, 64);
    float s2 = __shfl(score, b * 4 + 2, 64);
    float s3 = __shfl(score, b * 4 + 3, 64);
    float v0 = s0 + tr0, v1 = s1 + tr1, v2 = s2 + tr2, v3 = s3 + tr3;
    float best = v0; int arg = 0;
    if (v1 > best) { best = v1; arg = 1; }
    if (v2 > best) { best = v2; arg = 2; }
    if (v3 > best) { best = v3; arg = 3; }
    bp[t - 1][l] = (unsigned char)arg;   // first-max kept (matches np.argmax)
    score = best + em[((size_t)b * SEQ + t) * 4 + j];
  }
  score += endw[j];
  float f0 = __shfl(score, b * 4 + 0, 64);
  float f1 = __shfl(score, b * 4 + 1, 64);
  float f2 = __shfl(score, b * 4 + 2, 64);
  float f3 = __shfl(score, b * 4 + 3, 64);
  if (j == 0) {
    float bbv = f0; int last = 0;
    if (f1 > bbv) { bbv = f1; last = 1; }
    if (f2 > bbv) { bbv = f2; last = 2; }
    if (f3 > bbv) { bbv = f3; last = 3; }
    int tag = last;
    out[b * SEQ + (SEQ - 1)] = (float)tag;
    for (int t = SEQ - 2; t >= 0; t--) {
      tag = bp[t][b * 4 + tag];
      out[b * SEQ + t] = (float)tag;
    }
  }
}

// ------------------------------------------------------------------ launcher
extern "C" void kernel_launch(void* const* d_in, const int* in_sizes, int n_in,
                              void* d_out, int out_size, void* d_ws, size_t ws_size,
                              hipStream_t stream) {
  const float* emb      = (const float*)d_in[0];
  const float* l1f_wih  = (const float*)d_in[1];
  const float* l1f_whh  = (const float*)d_in[2];
  const float* l1f_b    = (const float*)d_in[3];
  const float* l1r_wih  = (const float*)d_in[4];
  const float* l1r_whh  = (const float*)d_in[5];
  const float* l1r_b    = (const float*)d_in[6];
  const float* attn_w   = (const float*)d_in[7];
  const float* attn_b   = (const float*)d_in[8];
  const float* l2f_wih  = (const float*)d_in[9];
  const float* l2f_whh  = (const float*)d_in[10];
  const float* l2f_b    = (const float*)d_in[11];
  const float* l2r_wih  = (const float*)d_in[12];
  const float* l2r_whh  = (const float*)d_in[13];
  const float* l2r_b    = (const float*)d_in[14];
  const float* crf_start= (const float*)d_in[15];
  const float* crf_end  = (const float*)d_in[16];
  const float* crf_trans= (const float*)d_in[17];

  float* ws = (float*)d_ws;
  const size_t NCH = (size_t)BATCH * CHUNK * G4;    // 3,145,728 (chunk xs, one dir)
  float* xs_f = ws;
  float* xs_r = xs_f + NCH;
  float* hs   = xs_r + NCH;                          // 3,145,728 (hf+hr accumulated)
  float* att  = xs_f;                                // overlay: xs dead after steps
  float* xs2  = xs_r;                                // overlay: 131072 floats
  float* hcur = hs + NCH;                            // 24576: [par][dir][b][HID]
  float* ccur = hcur + 4 * BATCH * HID;              // 12288
  float* h2   = ccur + 2 * BATCH * HID;              // 32768
  // total: ~38 MB

  k_init<<<dim3(4096), dim3(256), 0, stream>>>(hs, hcur, ccur);

  for (int c = 0; c < 4; c++) {
    k_proj1<<<dim3(24, 8, 2), dim3(256), 0, stream>>>(
        emb, l1f_wih, l1f_b, l1r_wih, l1r_b, xs_f, xs_r, c);
    for (int sl = 0; sl < CHUNK; sl++) {
      k_step1<<<dim3(96, 2), dim3(256), 0, stream>>>(
          l1f_whh, l1r_whh, xs_f, xs_r, hcur, ccur, hs, c * CHUNK + sl);
    }
  }

  k_attn<<<dim3(SEQ, BATCH), dim3(64), 0, stream>>>(hs, attn_w, attn_b, att);
  k_proj2<<<dim3(SEQ, BATCH), dim3(256), 0, stream>>>(
      hs, att, l2f_wih, l2f_b, l2r_wih, l2r_b, xs2);
  k_rec2<<<dim3(1), dim3(256), 0, stream>>>(xs2, l2f_whh, l2r_whh, h2);
  k_em<<<dim3(64), dim3(256), 0, stream>>>(h2, (float*)d_out);
  k_viterbi<<<dim3(1), dim3(32), 0, stream>>>((float*)d_out, crf_start, crf_end, crf_trans);
}